// Round 1
// baseline (64.473 us; speedup 1.0000x reference)
//
#include <hip/hip_runtime.h>
#include <math.h>

#define NPART 4096
#define HID 64
#define HI 8
#define IPB 16                 // particles (waves) per block
#define BLOCK (IPB * 64)       // 1024 threads

__global__ __launch_bounds__(BLOCK) void odefunc_kernel(
    const float* __restrict__ t_in,
    const float* __restrict__ z,
    const float* __restrict__ lnw,
    const float* __restrict__ W1,
    const float* __restrict__ b1,
    const float* __restrict__ Wv,
    const float* __restrict__ bv,
    const float* __restrict__ Wg,
    const float* __restrict__ bg,
    const float* __restrict__ Wi1,
    const float* __restrict__ bi1,
    const float* __restrict__ Wi2,
    const float* __restrict__ bi2,
    float* __restrict__ out)
{
    __shared__ float zs[NPART * 3];   // 48 KB
    const int tid = threadIdx.x;

    // stage all z into LDS (coalesced)
    for (int idx = tid; idx < NPART * 3; idx += BLOCK) zs[idx] = z[idx];
    __syncthreads();

    const int lane = tid & 63;
    const int wid  = tid >> 6;
    const int i    = blockIdx.x * IPB + wid;

    const float zi0 = zs[i * 3 + 0];
    const float zi1 = zs[i * 3 + 1];
    const float zi2 = zs[i * 3 + 2];
    const float tval = t_in[0];

    // ---- f_net MLP: lane = hidden unit (H == wavefront size) ----
    float pre = zi0 * W1[0 * HID + lane]
              + zi1 * W1[1 * HID + lane]
              + zi2 * W1[2 * HID + lane]
              + tval * W1[3 * HID + lane]
              + b1[lane];
    float h = tanhf(pre);
    float pv0 = h * Wv[lane * 3 + 0];
    float pv1 = h * Wv[lane * 3 + 1];
    float pv2 = h * Wv[lane * 3 + 2];
    float pg  = h * Wg[lane];
    #pragma unroll
    for (int s = 1; s < 64; s <<= 1) {
        pv0 += __shfl_xor(pv0, s);
        pv1 += __shfl_xor(pv1, s);
        pv2 += __shfl_xor(pv2, s);
        pg  += __shfl_xor(pg, s);
    }
    const float v0 = pv0 + bv[0];
    const float v1 = pv1 + bv[1];
    const float v2 = pv2 + bv[2];
    const float grow = pg + bg[0];

    // interaction params -> registers (wave-uniform)
    float wi1[HI], bc[HI], cc[HI];
    #pragma unroll
    for (int k = 0; k < HI; ++k) {
        wi1[k] = Wi1[k];
        bc[k]  = bi1[k];
        cc[k]  = Wi1[k] * Wi2[k];
    }

    // ---- pairwise force: lane l handles j = 64*t + l ----
    float fx = 0.f, fy = 0.f, fz = 0.f;
    for (int tt = 0; tt < NPART / 64; ++tt) {
        const int j = tt * 64 + lane;
        const float dx = zi0 - zs[j * 3 + 0];
        const float dy = zi1 - zs[j * 3 + 1];
        const float dz = zi2 - zs[j * 3 + 2];
        const float d2 = dx * dx + dy * dy + dz * dz + 1e-8f;
        const float r = sqrtf(d2);
        if (r < 0.5f && j != i) {
            float dU = 0.f;
            #pragma unroll
            for (int k = 0; k < HI; ++k) {
                const float th = tanhf(r * wi1[k] + bc[k]);
                dU += (1.0f - th * th) * cc[k];
            }
            const float wj = expf(lnw[j]);
            const float coeff = -(wj * dU) / (r * 16.0f);
            fx += coeff * dx;
            fy += coeff * dy;
            fz += coeff * dz;
        }
    }
    #pragma unroll
    for (int s = 1; s < 64; s <<= 1) {
        fx += __shfl_xor(fx, s);
        fy += __shfl_xor(fy, s);
        fz += __shfl_xor(fz, s);
    }

    if (lane == 0) {
        out[i * 3 + 0] = v0 + fx;
        out[i * 3 + 1] = v1 + fy;
        out[i * 3 + 2] = v2 + fz;
        out[NPART * 3 + i] = grow;                       // dlnw_dt
        const float wi = expf(lnw[i]);
        out[NPART * 3 + NPART + i] =
            (v0 * v0 + v1 * v1 + v2 * v2 + grow * grow) * wi;  // dm_dt
    }
}

extern "C" void kernel_launch(void* const* d_in, const int* in_sizes, int n_in,
                              void* d_out, int out_size, void* d_ws, size_t ws_size,
                              hipStream_t stream) {
    const float* t_in = (const float*)d_in[0];
    const float* z    = (const float*)d_in[1];
    const float* lnw  = (const float*)d_in[2];
    const float* W1   = (const float*)d_in[3];
    const float* b1   = (const float*)d_in[4];
    const float* Wv   = (const float*)d_in[5];
    const float* bv   = (const float*)d_in[6];
    const float* Wg   = (const float*)d_in[7];
    const float* bg   = (const float*)d_in[8];
    const float* Wi1  = (const float*)d_in[9];
    const float* bi1  = (const float*)d_in[10];
    const float* Wi2  = (const float*)d_in[11];
    const float* bi2  = (const float*)d_in[12];
    float* out = (float*)d_out;

    dim3 grid(NPART / IPB);   // 256 blocks
    dim3 block(BLOCK);        // 1024 threads = 16 waves
    odefunc_kernel<<<grid, block, 0, stream>>>(
        t_in, z, lnw, W1, b1, Wv, bv, Wg, bg, Wi1, bi1, Wi2, bi2, out);
}

// Round 2
// 19.430 us; speedup vs baseline: 3.3182x; 3.3182x over previous
//
#include <hip/hip_runtime.h>
#include <math.h>

#define NPART 4096
#define HID 64
#define HI 8
#define IPB 16                 // particles (waves) per block
#define BLOCK (IPB * 64)       // 1024 threads
#define CAP 512                // per-wave compacted-pair list capacity

__global__ __launch_bounds__(BLOCK) void odefunc_kernel(
    const float* __restrict__ t_in,
    const float* __restrict__ z,
    const float* __restrict__ lnw,
    const float* __restrict__ W1,
    const float* __restrict__ b1,
    const float* __restrict__ Wv,
    const float* __restrict__ bv,
    const float* __restrict__ Wg,
    const float* __restrict__ bg,
    const float* __restrict__ Wi1,
    const float* __restrict__ bi1,
    const float* __restrict__ Wi2,
    const float* __restrict__ bi2,
    float* __restrict__ out)
{
    __shared__ float4 zs[NPART];          // 64 KB: xyz + lnw in .w
    __shared__ unsigned short lists[IPB][CAP]; // 16 KB

    const int tid = threadIdx.x;

    // stage z (+ lnw packed in .w) into LDS
    for (int p = tid; p < NPART; p += BLOCK) {
        zs[p] = make_float4(z[p * 3 + 0], z[p * 3 + 1], z[p * 3 + 2], lnw[p]);
    }
    __syncthreads();

    const int lane = tid & 63;
    const int wid  = tid >> 6;
    const int i    = blockIdx.x * IPB + wid;

    const float4 zi = zs[i];
    const float tval = t_in[0];

    // ---- f_net MLP: lane = hidden unit (H == wavefront size) ----
    float pre = zi.x * W1[0 * HID + lane]
              + zi.y * W1[1 * HID + lane]
              + zi.z * W1[2 * HID + lane]
              + tval * W1[3 * HID + lane]
              + b1[lane];
    float h = tanhf(pre);
    float pv0 = h * Wv[lane * 3 + 0];
    float pv1 = h * Wv[lane * 3 + 1];
    float pv2 = h * Wv[lane * 3 + 2];
    float pg  = h * Wg[lane];
    #pragma unroll
    for (int s = 1; s < 64; s <<= 1) {
        pv0 += __shfl_xor(pv0, s);
        pv1 += __shfl_xor(pv1, s);
        pv2 += __shfl_xor(pv2, s);
        pg  += __shfl_xor(pg, s);
    }
    const float v0 = pv0 + bv[0];
    const float v1 = pv1 + bv[1];
    const float v2 = pv2 + bv[2];
    const float grow = pg + bg[0];

    // interaction constants (wave-uniform, in registers)
    // sech^2(x) = 4*s/(1+s)^2 with s = exp(-2x), x = r*Wi1[k] + bi1[k]
    float a_[HI], b_[HI], c_[HI];
    #pragma unroll
    for (int k = 0; k < HI; ++k) {
        a_[k] = -2.0f * Wi1[k];
        b_[k] = -2.0f * bi1[k];
        c_[k] = 4.0f * Wi1[k] * Wi2[k];
    }

    float fx = 0.f, fy = 0.f, fz = 0.f;
    unsigned short* myl = lists[wid];
    const unsigned long long lt_mask = (1ull << lane) - 1ull;
    int cnt = 0;

    auto process = [&](int n) {
        for (int base = 0; base < n; base += 64) {
            const int k = base + lane;
            const bool valid = (k < n);
            const int jj = valid ? (int)myl[k] : i;
            const float4 zj = zs[jj];
            const float dx = zi.x - zj.x;
            const float dy = zi.y - zj.y;
            const float dz = zi.z - zj.z;
            const float d2 = dx * dx + dy * dy + dz * dz + 1e-8f;
            const float r = sqrtf(d2);
            const float invr = __builtin_amdgcn_rcpf(r);
            float dU = 0.f;
            #pragma unroll
            for (int kk = 0; kk < HI; ++kk) {
                const float e = fmaf(r, a_[kk], b_[kk]);
                const float s = __expf(e);
                const float den = 1.0f + s;
                dU = fmaf(c_[kk] * s, __builtin_amdgcn_rcpf(den * den), dU);
            }
            const float wj = __expf(zj.w);
            const float coeff = valid ? (-0.0625f) * wj * dU * invr : 0.0f;
            fx = fmaf(coeff, dx, fx);
            fy = fmaf(coeff, dy, fy);
            fz = fmaf(coeff, dz, fz);
        }
    };

    // ---- phase 1: cheap distance scan + compaction ----
    for (int tt = 0; tt < NPART / 64; ++tt) {
        const int j = tt * 64 + lane;
        const float4 zj = zs[j];
        const float dx = zi.x - zj.x;
        const float dy = zi.y - zj.y;
        const float dz = zi.z - zj.z;
        const float d2 = dx * dx + dy * dy + dz * dz + 1e-8f;
        const bool pred = (d2 < 0.25f) && (j != i);
        const unsigned long long bal = __ballot(pred);
        if (bal) {
            const int pos = cnt + __popcll(bal & lt_mask);
            if (pred) myl[pos] = (unsigned short)j;
            cnt += __popcll(bal);
            if (cnt > CAP - 64) { process(cnt); cnt = 0; }
        }
    }
    // ---- phase 2: process remaining compacted pairs ----
    process(cnt);

    #pragma unroll
    for (int s = 1; s < 64; s <<= 1) {
        fx += __shfl_xor(fx, s);
        fy += __shfl_xor(fy, s);
        fz += __shfl_xor(fz, s);
    }

    if (lane == 0) {
        out[i * 3 + 0] = v0 + fx;
        out[i * 3 + 1] = v1 + fy;
        out[i * 3 + 2] = v2 + fz;
        out[NPART * 3 + i] = grow;                        // dlnw_dt
        const float wi = __expf(zi.w);
        out[NPART * 3 + NPART + i] =
            (v0 * v0 + v1 * v1 + v2 * v2 + grow * grow) * wi;  // dm_dt
    }
}

extern "C" void kernel_launch(void* const* d_in, const int* in_sizes, int n_in,
                              void* d_out, int out_size, void* d_ws, size_t ws_size,
                              hipStream_t stream) {
    const float* t_in = (const float*)d_in[0];
    const float* z    = (const float*)d_in[1];
    const float* lnw  = (const float*)d_in[2];
    const float* W1   = (const float*)d_in[3];
    const float* b1   = (const float*)d_in[4];
    const float* Wv   = (const float*)d_in[5];
    const float* bv   = (const float*)d_in[6];
    const float* Wg   = (const float*)d_in[7];
    const float* bg   = (const float*)d_in[8];
    const float* Wi1  = (const float*)d_in[9];
    const float* bi1  = (const float*)d_in[10];
    const float* Wi2  = (const float*)d_in[11];
    const float* bi2  = (const float*)d_in[12];
    float* out = (float*)d_out;

    dim3 grid(NPART / IPB);   // 256 blocks -> 1 per CU
    dim3 block(BLOCK);        // 1024 threads = 16 waves
    odefunc_kernel<<<grid, block, 0, stream>>>(
        t_in, z, lnw, W1, b1, Wv, bv, Wg, bg, Wi1, bi1, Wi2, bi2, out);
}

// Round 3
// 19.129 us; speedup vs baseline: 3.3703x; 1.0157x over previous
//
#include <hip/hip_runtime.h>
#include <math.h>

#define NPART 4096
#define HID 64
#define HI 8
#define IPB 8                   // particles per block
#define WPB 16                  // waves per block (2 waves per particle)
#define BLOCK (WPB * 64)        // 1024 threads
#define CAP 448                 // per-wave compacted-pair list capacity
#define HRANGE (NPART / 2)      // j-range per wave
#define HTILES (HRANGE / 64)    // 32 scan iterations per wave

__global__ __launch_bounds__(BLOCK) void odefunc_kernel(
    const float* __restrict__ t_in,
    const float* __restrict__ z,
    const float* __restrict__ lnw,
    const float* __restrict__ W1,
    const float* __restrict__ b1,
    const float* __restrict__ Wv,
    const float* __restrict__ bv,
    const float* __restrict__ Wg,
    const float* __restrict__ bg,
    const float* __restrict__ Wi1,
    const float* __restrict__ bi1,
    const float* __restrict__ Wi2,
    const float* __restrict__ bi2,
    float* __restrict__ out)
{
    __shared__ float4 zs[NPART];               // 64 KB: xyz + lnw in .w
    __shared__ unsigned short lists[WPB][CAP]; // 14 KB
    __shared__ float pf[IPB][3];               // half-1 partial forces

    const int tid = threadIdx.x;

    // stage z (+ lnw packed in .w) into LDS
    for (int p = tid; p < NPART; p += BLOCK) {
        zs[p] = make_float4(z[p * 3 + 0], z[p * 3 + 1], z[p * 3 + 2], lnw[p]);
    }
    __syncthreads();

    const int lane = tid & 63;
    const int wid  = tid >> 6;
    const int pidx = wid & (IPB - 1);       // particle slot in block
    const int half = wid >> 3;              // which half of j-range
    const int i    = blockIdx.x * IPB + pidx;

    const float4 zi = zs[i];

    float v0 = 0.f, v1 = 0.f, v2 = 0.f, grow = 0.f;
    if (half == 0) {
        // ---- f_net MLP: lane = hidden unit (H == wavefront size) ----
        const float tval = t_in[0];
        float pre = zi.x * W1[0 * HID + lane]
                  + zi.y * W1[1 * HID + lane]
                  + zi.z * W1[2 * HID + lane]
                  + tval * W1[3 * HID + lane]
                  + b1[lane];
        float h = tanhf(pre);
        float pv0 = h * Wv[lane * 3 + 0];
        float pv1 = h * Wv[lane * 3 + 1];
        float pv2 = h * Wv[lane * 3 + 2];
        float pg  = h * Wg[lane];
        #pragma unroll
        for (int s = 1; s < 64; s <<= 1) {
            pv0 += __shfl_xor(pv0, s);
            pv1 += __shfl_xor(pv1, s);
            pv2 += __shfl_xor(pv2, s);
            pg  += __shfl_xor(pg, s);
        }
        v0 = pv0 + bv[0];
        v1 = pv1 + bv[1];
        v2 = pv2 + bv[2];
        grow = pg + bg[0];
    }

    // interaction constants (wave-uniform, in registers)
    // sech^2(x) = 4*s/(1+s)^2 with s = exp(-2x), x = r*Wi1[k] + bi1[k]
    float a_[HI], b_[HI], c_[HI];
    #pragma unroll
    for (int k = 0; k < HI; ++k) {
        a_[k] = -2.0f * Wi1[k];
        b_[k] = -2.0f * bi1[k];
        c_[k] = 4.0f * Wi1[k] * Wi2[k];
    }

    float fx = 0.f, fy = 0.f, fz = 0.f;
    unsigned short* myl = lists[wid];
    const unsigned long long lt_mask = (1ull << lane) - 1ull;
    int cnt = 0;

    auto process = [&](int n) {
        for (int base = 0; base < n; base += 64) {
            const int k = base + lane;
            const bool valid = (k < n);
            const int jj = valid ? (int)myl[k] : i;
            const float4 zj = zs[jj];
            const float dx = zi.x - zj.x;
            const float dy = zi.y - zj.y;
            const float dz = zi.z - zj.z;
            const float d2 = dx * dx + dy * dy + dz * dz + 1e-8f;
            const float r = sqrtf(d2);
            const float invr = __builtin_amdgcn_rcpf(r);
            float dU = 0.f;
            #pragma unroll
            for (int kk = 0; kk < HI; ++kk) {
                const float e = fmaf(r, a_[kk], b_[kk]);
                const float s = __expf(e);
                const float den = 1.0f + s;
                dU = fmaf(c_[kk] * s, __builtin_amdgcn_rcpf(den * den), dU);
            }
            const float wj = __expf(zj.w);
            const float coeff = valid ? (-0.0625f) * wj * dU * invr : 0.0f;
            fx = fmaf(coeff, dx, fx);
            fy = fmaf(coeff, dy, fy);
            fz = fmaf(coeff, dz, fz);
        }
    };

    // ---- phase 1: cheap distance scan + compaction (this wave's half) ----
    const int jbase = half * HRANGE;
    float4 zj = zs[jbase + lane];                 // software-pipelined lookahead
    for (int tt = 0; tt < HTILES; ++tt) {
        const int j = jbase + tt * 64 + lane;
        const float4 zjn = zs[jbase + ((tt + 1) & (HTILES - 1)) * 64 + lane];
        const float dx = zi.x - zj.x;
        const float dy = zi.y - zj.y;
        const float dz = zi.z - zj.z;
        const float d2 = dx * dx + dy * dy + dz * dz + 1e-8f;
        const bool pred = (d2 < 0.25f) && (j != i);
        const unsigned long long bal = __ballot(pred);
        if (bal) {
            const int pos = cnt + __popcll(bal & lt_mask);
            if (pred) myl[pos] = (unsigned short)j;
            cnt += __popcll(bal);
            if (cnt > CAP - 64) { process(cnt); cnt = 0; }
        }
        zj = zjn;
    }
    // ---- phase 2: process remaining compacted pairs ----
    process(cnt);

    #pragma unroll
    for (int s = 1; s < 64; s <<= 1) {
        fx += __shfl_xor(fx, s);
        fy += __shfl_xor(fy, s);
        fz += __shfl_xor(fz, s);
    }

    // half-1 waves publish partial force; half-0 waves combine + write out
    if (half == 1 && lane == 0) {
        pf[pidx][0] = fx;
        pf[pidx][1] = fy;
        pf[pidx][2] = fz;
    }
    __syncthreads();

    if (half == 0 && lane == 0) {
        const float gfx = fx + pf[pidx][0];
        const float gfy = fy + pf[pidx][1];
        const float gfz = fz + pf[pidx][2];
        out[i * 3 + 0] = v0 + gfx;
        out[i * 3 + 1] = v1 + gfy;
        out[i * 3 + 2] = v2 + gfz;
        out[NPART * 3 + i] = grow;                        // dlnw_dt
        const float wi = __expf(zi.w);
        out[NPART * 3 + NPART + i] =
            (v0 * v0 + v1 * v1 + v2 * v2 + grow * grow) * wi;  // dm_dt
    }
}

extern "C" void kernel_launch(void* const* d_in, const int* in_sizes, int n_in,
                              void* d_out, int out_size, void* d_ws, size_t ws_size,
                              hipStream_t stream) {
    const float* t_in = (const float*)d_in[0];
    const float* z    = (const float*)d_in[1];
    const float* lnw  = (const float*)d_in[2];
    const float* W1   = (const float*)d_in[3];
    const float* b1   = (const float*)d_in[4];
    const float* Wv   = (const float*)d_in[5];
    const float* bv   = (const float*)d_in[6];
    const float* Wg   = (const float*)d_in[7];
    const float* bg   = (const float*)d_in[8];
    const float* Wi1  = (const float*)d_in[9];
    const float* bi1  = (const float*)d_in[10];
    const float* Wi2  = (const float*)d_in[11];
    const float* bi2  = (const float*)d_in[12];
    float* out = (float*)d_out;

    dim3 grid(NPART / IPB);   // 512 blocks -> 2 per CU
    dim3 block(BLOCK);        // 1024 threads = 16 waves
    odefunc_kernel<<<grid, block, 0, stream>>>(
        t_in, z, lnw, W1, b1, Wv, bv, Wg, bg, Wi1, bi1, Wi2, bi2, out);
}

// Round 4
// 18.038 us; speedup vs baseline: 3.5742x; 1.0605x over previous
//
#include <hip/hip_runtime.h>
#include <hip/hip_fp16.h>
#include <math.h>

#define NPART 4096
#define HID 64
#define HI 8
#define IPB 8                   // particles per block
#define WPB 16                  // waves per block (2 waves per particle)
#define BLOCK (WPB * 64)        // 1024 threads
#define CAP 384                 // per-wave compacted list capacity
#define NPAIR (NPART / 2)       // 2048 f16x2 pair slots
#define HPAIR (NPAIR / 2)       // 1024 pair slots per half-range
#define HTILE (HPAIR / 64)      // 16 scan tiles per wave
#define TBL 2048                // dU(r) table size
#define TSCALE 4094.0f          // (TBL-1)/0.5

struct alignas(8) XYPair { __half2 x, y; };

__global__ __launch_bounds__(BLOCK) void odefunc_kernel(
    const float* __restrict__ t_in,
    const float* __restrict__ z,
    const float* __restrict__ lnw,
    const float* __restrict__ W1,
    const float* __restrict__ b1,
    const float* __restrict__ Wv,
    const float* __restrict__ bv,
    const float* __restrict__ Wg,
    const float* __restrict__ bg,
    const float* __restrict__ Wi1,
    const float* __restrict__ bi1,
    const float* __restrict__ Wi2,
    const float* __restrict__ bi2,
    float* __restrict__ out)
{
    __shared__ XYPair  sXY[NPAIR];            // 16 KB  (x,y f16x2 for j=2q,2q+1)
    __shared__ __half2 sZ[NPAIR];             //  8 KB
    __shared__ float   sW[NPART];             // 16 KB  exp(lnw)
    __shared__ float   sT[TBL];               //  8 KB  dU(r) table
    __shared__ unsigned short lists[WPB][CAP];// 12 KB
    __shared__ float   pf[IPB][3];

    const int tid = threadIdx.x;

    // ---- staging: f16 scan tables, weights, dU table ----
    for (int q = tid; q < NPAIR; q += BLOCK) {
        const float x0 = z[6 * q + 0], y0 = z[6 * q + 1], z0 = z[6 * q + 2];
        const float x1 = z[6 * q + 3], y1 = z[6 * q + 4], z1 = z[6 * q + 5];
        XYPair p;
        p.x = __floats2half2_rn(x0, x1);
        p.y = __floats2half2_rn(y0, y1);
        sXY[q] = p;
        sZ[q]  = __floats2half2_rn(z0, z1);
    }
    for (int p = tid; p < NPART; p += BLOCK) sW[p] = __expf(lnw[p]);
    for (int k2 = tid; k2 < TBL; k2 += BLOCK) {
        const float r = (float)k2 * (0.5f / (float)(TBL - 1));
        float acc = 0.f;
        #pragma unroll
        for (int kk = 0; kk < HI; ++kk) {
            // dU/dr term: c*sech^2(r*w+b) = 4c*s/(1+s)^2, s=exp(-2(r*w+b))
            const float s = __expf(-2.0f * fmaf(r, Wi1[kk], bi1[kk]));
            const float den = 1.0f + s;
            acc += 4.0f * Wi1[kk] * Wi2[kk] * s *
                   __builtin_amdgcn_rcpf(den * den);
        }
        sT[k2] = acc;
    }
    __syncthreads();

    const int lane = tid & 63;
    const int wid  = tid >> 6;
    const int pidx = wid & (IPB - 1);
    const int half = wid >> 3;
    const int i    = blockIdx.x * IPB + pidx;

    const float zix = z[3 * i + 0];
    const float ziy = z[3 * i + 1];
    const float ziz = z[3 * i + 2];

    float v0 = 0.f, v1 = 0.f, v2 = 0.f, grow = 0.f;
    if (half == 0) {
        // ---- f_net MLP: lane = hidden unit ----
        const float tval = t_in[0];
        float pre = zix * W1[0 * HID + lane]
                  + ziy * W1[1 * HID + lane]
                  + ziz * W1[2 * HID + lane]
                  + tval * W1[3 * HID + lane]
                  + b1[lane];
        float h = tanhf(pre);
        float pv0 = h * Wv[lane * 3 + 0];
        float pv1 = h * Wv[lane * 3 + 1];
        float pv2 = h * Wv[lane * 3 + 2];
        float pg  = h * Wg[lane];
        #pragma unroll
        for (int s = 1; s < 64; s <<= 1) {
            pv0 += __shfl_xor(pv0, s);
            pv1 += __shfl_xor(pv1, s);
            pv2 += __shfl_xor(pv2, s);
            pg  += __shfl_xor(pg, s);
        }
        v0 = pv0 + bv[0];
        v1 = pv1 + bv[1];
        v2 = pv2 + bv[2];
        grow = pg + bg[0];
    }

    float fx = 0.f, fy = 0.f, fz = 0.f;
    unsigned short* myl = lists[wid];
    int cnt = 0;

    auto process = [&](int n) {
        for (int base = 0; base < n; base += 64) {
            const int k = base + lane;
            const bool valid = (k < n);
            const int jj = valid ? (int)myl[k] : i;
            const float dx = zix - z[3 * jj + 0];
            const float dy = ziy - z[3 * jj + 1];
            const float dz = ziz - z[3 * jj + 2];
            const float d2 = dx * dx + dy * dy + dz * dz + 1e-8f;
            const bool ok = valid && (d2 < 0.25f) && (jj != i);  // exact recheck
            const float r = sqrtf(d2);
            const float u = r * TSCALE;
            int i0 = (int)u;
            i0 = i0 > (TBL - 2) ? (TBL - 2) : i0;
            const float fr = u - (float)i0;
            const float t0 = sT[i0], t1 = sT[i0 + 1];
            const float dU = fmaf(fr, t1 - t0, t0);
            const float invr = __builtin_amdgcn_rcpf(r);
            const float coeff = ok ? (-0.0625f) * sW[jj] * dU * invr : 0.0f;
            fx = fmaf(coeff, dx, fx);
            fy = fmaf(coeff, dy, fy);
            fz = fmaf(coeff, dz, fz);
        }
    };

    // ---- phase 1: packed-f16 scan with conservative band ----
    const __half2 hxi = __float2half2_rn(zix);
    const __half2 hyi = __float2half2_rn(ziy);
    const __half2 hzi = __float2half2_rn(ziz);
    const __half  thr = __float2half_rn(0.26f);   // band covers f16 error
    const int qbase = half * HPAIR;

    #pragma unroll 4
    for (int tt = 0; tt < HTILE; ++tt) {
        const int q = qbase + tt * 64 + lane;
        const XYPair  pxy = sXY[q];
        const __half2 pz  = sZ[q];
        const __half2 dx = __hsub2(hxi, pxy.x);
        const __half2 dy = __hsub2(hyi, pxy.y);
        const __half2 dz = __hsub2(hzi, pz);
        const __half2 d2 = __hfma2(dx, dx, __hfma2(dy, dy, __hmul2(dz, dz)));
        const bool f0 = __hlt(__low2half(d2), thr);
        const bool f1 = __hlt(__high2half(d2), thr);
        const unsigned long long b0 = __ballot(f0);
        {
            const unsigned int lo = (unsigned int)b0, hi = (unsigned int)(b0 >> 32);
            const int pre = __builtin_amdgcn_mbcnt_hi(hi, __builtin_amdgcn_mbcnt_lo(lo, 0u));
            if (f0) myl[cnt + pre] = (unsigned short)(2 * q);
            cnt += __popcll(b0);
        }
        const unsigned long long b1 = __ballot(f1);
        {
            const unsigned int lo = (unsigned int)b1, hi = (unsigned int)(b1 >> 32);
            const int pre = __builtin_amdgcn_mbcnt_hi(hi, __builtin_amdgcn_mbcnt_lo(lo, 0u));
            if (f1) myl[cnt + pre] = (unsigned short)(2 * q + 1);
            cnt += __popcll(b1);
        }
        if (cnt > CAP - 128) { process(cnt); cnt = 0; }
    }
    process(cnt);

    #pragma unroll
    for (int s = 1; s < 64; s <<= 1) {
        fx += __shfl_xor(fx, s);
        fy += __shfl_xor(fy, s);
        fz += __shfl_xor(fz, s);
    }

    if (half == 1 && lane == 0) {
        pf[pidx][0] = fx;
        pf[pidx][1] = fy;
        pf[pidx][2] = fz;
    }
    __syncthreads();

    if (half == 0 && lane == 0) {
        const float gfx = fx + pf[pidx][0];
        const float gfy = fy + pf[pidx][1];
        const float gfz = fz + pf[pidx][2];
        out[i * 3 + 0] = v0 + gfx;
        out[i * 3 + 1] = v1 + gfy;
        out[i * 3 + 2] = v2 + gfz;
        out[NPART * 3 + i] = grow;                         // dlnw_dt
        const float wi = sW[i];
        out[NPART * 3 + NPART + i] =
            (v0 * v0 + v1 * v1 + v2 * v2 + grow * grow) * wi;  // dm_dt
    }
}

extern "C" void kernel_launch(void* const* d_in, const int* in_sizes, int n_in,
                              void* d_out, int out_size, void* d_ws, size_t ws_size,
                              hipStream_t stream) {
    const float* t_in = (const float*)d_in[0];
    const float* z    = (const float*)d_in[1];
    const float* lnw  = (const float*)d_in[2];
    const float* W1   = (const float*)d_in[3];
    const float* b1   = (const float*)d_in[4];
    const float* Wv   = (const float*)d_in[5];
    const float* bv   = (const float*)d_in[6];
    const float* Wg   = (const float*)d_in[7];
    const float* bg   = (const float*)d_in[8];
    const float* Wi1  = (const float*)d_in[9];
    const float* bi1  = (const float*)d_in[10];
    const float* Wi2  = (const float*)d_in[11];
    const float* bi2  = (const float*)d_in[12];
    float* out = (float*)d_out;

    dim3 grid(NPART / IPB);   // 512 blocks -> 2 per CU
    dim3 block(BLOCK);        // 1024 threads = 16 waves
    odefunc_kernel<<<grid, block, 0, stream>>>(
        t_in, z, lnw, W1, b1, Wv, bv, Wg, bg, Wi1, bi1, Wi2, bi2, out);
}